// Round 21
// baseline (136.879 us; speedup 1.0000x reference)
//
#include <hip/hip_runtime.h>
#include <hip/hip_bf16.h>

// Problem constants
#define SQn 2048
#define SKn 2048
#define DMn 1024
#define NHn 16
#define DHn 64

typedef __attribute__((ext_vector_type(8))) short bf16x8;
typedef __attribute__((ext_vector_type(4))) float f32x4;

#define QSCALE 0.1803368801f  /* (1/sqrt(64)) / ln2 : folds softmax scale + exp->exp2 */

#define FBAR()                                     \
  __builtin_amdgcn_sched_barrier(0);               \
  asm volatile("s_barrier" ::: "memory");          \
  __builtin_amdgcn_sched_barrier(0)

__device__ __forceinline__ short f2bf(float f) {
  union { float f; unsigned u; } a; a.f = f;
  return (short)((a.u + 0x7FFFu + ((a.u >> 16) & 1u)) >> 16);  // RNE
}

__device__ __forceinline__ unsigned cvt_pk_bf16(float lo, float hi) {
  unsigned r;
  asm("v_cvt_pk_bf16_f32 %0, %1, %2" : "=v"(r) : "v"(lo), "v"(hi));
  return r;
}

__device__ __forceinline__ void gload16(const void* g, void* l) {
  __builtin_amdgcn_global_load_lds(
      (__attribute__((address_space(1))) void*)g,
      (__attribute__((address_space(3))) void*)l, 16, 0, 0);
}

// ---------------- fused preprocessing: casts + weight transposes + mask scan ----
#define NCASTB 12288
__global__ __launch_bounds__(256) void prep(
    const float* __restrict__ Q, const float* __restrict__ K, const float* __restrict__ V,
    const float* __restrict__ W0, const float* __restrict__ W1,
    const float* __restrict__ W2, const float* __restrict__ W3,
    const int* __restrict__ mask,
    short* __restrict__ qkvOut, short* __restrict__ WtBase,
    int* __restrict__ inv, int* __restrict__ Lb) {
  const int blk = blockIdx.x;
  const int tid = threadIdx.x;
  __shared__ float t[32][33];
  __shared__ int part[256];
  __shared__ int base[256];
  __shared__ int totL;

  if (blk < NCASTB) {
    const int n4each = (2 * 2048 * 1024) / 4;
    int i = blk * 256 + tid;
    const float* src;
    int j = i;
    if (i < n4each) src = Q;
    else if (i < 2 * n4each) { src = K; j = i - n4each; }
    else { src = V; j = i - 2 * n4each; }
    float4 f = ((const float4*)src)[j];
    short4 o;
    o.x = f2bf(f.x); o.y = f2bf(f.y); o.z = f2bf(f.z); o.w = f2bf(f.w);
    ((short4*)qkvOut)[i] = o;
  } else if (blk < NCASTB + 4096) {
    const int tt = blk - NCASTB;
    const int z = tt >> 10;
    const int rem = tt & 1023;
    const float* W = (z == 0) ? W0 : (z == 1) ? W1 : (z == 2) ? W2 : W3;
    short* Wt = WtBase + (size_t)z * DMn * DMn;
    const int bx = (rem & 31) * 32;   // N range
    const int by = (rem >> 5) * 32;   // K range
    const int tx = tid & 31, ty = tid >> 5;  // 32 x 8
#pragma unroll
    for (int j = 0; j < 4; ++j)
      t[ty + j * 8][tx] = W[(size_t)(by + ty + j * 8) * DMn + bx + tx];
    __syncthreads();
#pragma unroll
    for (int j = 0; j < 4; ++j)
      Wt[(size_t)(bx + ty + j * 8) * DMn + by + tx] = f2bf(t[tx][ty + j * 8]);
  } else {
    const int b = blk - NCASTB - 4096;
    const int* m = mask + b * SKn;
    int v[8];
    int s0 = 0;
#pragma unroll
    for (int j = 0; j < 8; ++j) { v[j] = m[tid * 8 + j] ? 1 : 0; s0 += v[j]; }
    part[tid] = s0;
    __syncthreads();
    if (tid == 0) {
      int acc = 0;
      for (int i = 0; i < 256; ++i) { base[i] = acc; acc += part[i]; }
      Lb[b] = acc;
      totL = acc;
    }
    __syncthreads();
    int acc = base[tid];            // # valid keys before this thread's span
    int* ip = inv + b * SKn;
#pragma unroll
    for (int j = 0; j < 8; ++j) {
      int s = tid * 8 + j;
      int c = v[j] ? acc : (totL + s - acc);  // stable partition, bijective
      ip[c] = s;
      acc += v[j];
    }
  }
}

// ---------------- projection GEMM: 128x256 tile, BK=32, 512 thr, T4 pipeline ----
// BN 128->256 halves A-restaging (bytes model: time ~ staged bytes/CU at
// ~25GB/s/CU). Grid 384 -> 256 ACTIVE blocks after dead-block exits = 1/CU,
// 786KB staged per block (was 1MB/CU). Depth-2 counted-vmcnt keeps loads in
// flight across compute (uniform 3 loads/thread/tile -> vmcnt(3)).
__global__ __launch_bounds__(512) void gemm_bt3(
    const short* __restrict__ A0, const short* __restrict__ A1, const short* __restrict__ A2,
    const short* __restrict__ B0, const short* __restrict__ B1, const short* __restrict__ B2,
    const float* __restrict__ c0, const float* __restrict__ c1, const float* __restrict__ c2,
    short* __restrict__ O0, short* __restrict__ O1, short* __restrict__ O2,
    const int* __restrict__ invp, const int* __restrict__ Lp) {
  constexpr int K = 1024;
  const int z = blockIdx.z;
  const int bm = blockIdx.x * 128, bn = blockIdx.y * 256;

  if (z != 0 && (bm & 2047) >= Lp[bm >> 11]) return;

  const short* A  = (z == 0) ? A0 : (z == 1) ? A1 : A2;
  const short* Bt = (z == 0) ? B0 : (z == 1) ? B1 : B2;
  const float* bias = (z == 0) ? c0 : (z == 1) ? c1 : c2;
  short* Cout = (z == 0) ? O0 : (z == 1) ? O1 : O2;

  __shared__ short As[2][128 * 32];   // 8KB each
  __shared__ short Bs[2][256 * 32];   // 16KB each
  const int tid = threadIdx.x;
  const int lane = tid & 63;
  const int wid = tid >> 6;            // 0..7
  const int wr = wid >> 2, wc = wid & 3;   // wave tile 64x64 (2 x 4 waves)

  f32x4 acc[4][4] = {};

  const int srow = tid >> 2;           // 0..127
  const int scol = (tid & 3) * 8;
  int srcRow = bm + srow;
  if (z != 0) srcRow = (srcRow & ~2047) | invp[srcRow];
  const short* Arow = A + (size_t)srcRow * K;         // A: 1 chunk/thread
  const short* Brow0 = Bt + (size_t)(bn + srow) * K;  // B rows 0..127
  const short* Brow1 = Brow0 + (size_t)128 * K;       // B rows 128..255

#define GSTG(buf, k0)                                      \
  gload16(Arow + (k0) + scol,  As[buf] + tid * 8);         \
  gload16(Brow0 + (k0) + scol, Bs[buf] + tid * 8);         \
  gload16(Brow1 + (k0) + scol, Bs[buf] + 4096 + tid * 8);

  GSTG(0, 0);
  GSTG(1, 32);

  const int rowA = wr * 64 + (lane & 15);
  const int rowB = wc * 64 + (lane & 15);
  const int ko = (lane >> 4) * 8;

  for (int t = 0; t < 32; ++t) {
    const int cur = t & 1;
    if (t < 31) asm volatile("s_waitcnt vmcnt(3)" ::: "memory");
    else        asm volatile("s_waitcnt vmcnt(0)" ::: "memory");
    FBAR();

    bf16x8 a[4], b[4];
#pragma unroll
    for (int m = 0; m < 4; ++m) a[m] = *(const bf16x8*)(As[cur] + (rowA + m * 16) * 32 + ko);
#pragma unroll
    for (int n = 0; n < 4; ++n) b[n] = *(const bf16x8*)(Bs[cur] + (rowB + n * 16) * 32 + ko);
    __builtin_amdgcn_s_setprio(1);
#pragma unroll
    for (int m = 0; m < 4; ++m)
#pragma unroll
      for (int n = 0; n < 4; ++n)
        acc[m][n] = __builtin_amdgcn_mfma_f32_16x16x32_bf16(a[m], b[n], acc[m][n], 0, 0, 0);
    __builtin_amdgcn_s_setprio(0);

    FBAR();
    if (t < 30) { GSTG(cur, t * 32 + 64); }
  }
#undef GSTG

  // epilogue: C/D layout col=lane&15, row=(lane>>4)*4+i
  const int crow0 = bm + wr * 64 + ((lane >> 4) * 4);
  const int ccol0 = bn + wc * 64 + (lane & 15);
  float bv[4];
#pragma unroll
  for (int n = 0; n < 4; ++n) bv[n] = bias[ccol0 + n * 16];
#pragma unroll
  for (int m = 0; m < 4; ++m)
#pragma unroll
    for (int i = 0; i < 4; ++i) {
      int row = crow0 + m * 16 + i;
      int bb = row >> 11, s = row & 2047;   // s = compacted index for z!=0
#pragma unroll
      for (int n = 0; n < 4; ++n) {
        int col = ccol0 + n * 16;
        float val = acc[m][n][i] + bv[n];
        int hh = col >> 6, d = col & 63;    // DH=64
        if (z == 2) {  // V^T: [b][h][d][s_c]
          Cout[((((size_t)bb * NHn + hh) * DHn + d) << 11) + s] = f2bf(val);
        } else {
          if (z == 0) val *= QSCALE;
          Cout[((((size_t)bb * NHn + hh) * SQn + s) << 6) + d] = f2bf(val);
        }
      }
    }
}

// ---------------- final GEMM: 128x64, BK=32, 256 thr, T4 counted-vmcnt ----------
__global__ __launch_bounds__(256) void gemm_n64(const short* __restrict__ A,
                                                const short* __restrict__ Bt,
                                                const float* __restrict__ bias,
                                                float* __restrict__ C) {
  constexpr int K = 1024, N = 1024;
  __shared__ short As[2][128 * 32];
  __shared__ short Bs[2][64 * 32];
  const int tid = threadIdx.x;
  const int lane = tid & 63;
  const int wid = tid >> 6;
  const int wr = wid >> 1, wc = wid & 1;   // waves 2x2, wave tile 64x32
  const int bm = blockIdx.x * 128, bn = blockIdx.y * 64;

  f32x4 acc[4][2] = {};

  const int srow = tid >> 2;               // 0..63
  const int scol = (tid & 3) * 8;
  const short* Ag = A + (size_t)bm * K;
  const short* Bg = Bt + (size_t)bn * K;

#define GSTG(buf, k0)                                                             \
  gload16(Ag + (size_t)srow * K + (k0) + scol,        As[buf] + tid * 8);         \
  gload16(Ag + (size_t)(srow + 64) * K + (k0) + scol, As[buf] + 2048 + tid * 8);  \
  gload16(Bg + (size_t)srow * K + (k0) + scol,        Bs[buf] + tid * 8);

  GSTG(0, 0);
  GSTG(1, 32);

  const int rowA = wr * 64 + (lane & 15);
  const int rowB = wc * 32 + (lane & 15);
  const int ko = (lane >> 4) * 8;

  for (int t = 0; t < 32; ++t) {
    const int cur = t & 1;
    if (t < 31) asm volatile("s_waitcnt vmcnt(3)" ::: "memory");
    else        asm volatile("s_waitcnt vmcnt(0)" ::: "memory");
    FBAR();

    bf16x8 a[4], b[2];
#pragma unroll
    for (int m = 0; m < 4; ++m) a[m] = *(const bf16x8*)(As[cur] + (rowA + m * 16) * 32 + ko);
#pragma unroll
    for (int n = 0; n < 2; ++n) b[n] = *(const bf16x8*)(Bs[cur] + (rowB + n * 16) * 32 + ko);
    __builtin_amdgcn_s_setprio(1);
#pragma unroll
    for (int m = 0; m < 4; ++m)
#pragma unroll
      for (int n = 0; n < 2; ++n)
        acc[m][n] = __builtin_amdgcn_mfma_f32_16x16x32_bf16(a[m], b[n], acc[m][n], 0, 0, 0);
    __builtin_amdgcn_s_setprio(0);

    FBAR();
    if (t < 30) { GSTG(cur, t * 32 + 64); }
  }
#undef GSTG

  const int crow0 = bm + wr * 64 + ((lane >> 4) * 4);
  const int ccol0 = bn + wc * 32 + (lane & 15);
#pragma unroll
  for (int m = 0; m < 4; ++m)
#pragma unroll
    for (int n = 0; n < 2; ++n) {
      int col = ccol0 + n * 16;
      float bv = bias[col];
#pragma unroll
      for (int i = 0; i < 4; ++i) {
        int row = crow0 + m * 16 + i;
        C[(size_t)row * N + col] = acc[m][n][i] + bv;
      }
    }
}

// ---------------- fused flash attention, QBLK=128 (r19-verified config) ---------
// LDS = 2*8K (K) + 2*8K (V) + 16K (P) = 49152; 512 blocks, 2/CU.
__global__ __launch_bounds__(512) void attn(const short* __restrict__ q,
                                            const short* __restrict__ k,
                                            const short* __restrict__ vt,
                                            const int* __restrict__ Lb,
                                            short* __restrict__ out) {
  __shared__ short Ks[2][64 * 64];   // [key][d], chunk-swizzled ^(key&7)
  __shared__ short Vs[2][64 * 64];   // [d][key], chunk-swizzled ^(d&7)
  __shared__ short Ps[8][16 * 64];   // per-wave P, 8B-slot XOR swizzle

  const int tid = threadIdx.x;
  const int lane = tid & 63;
  const int w = tid >> 6;            // 0..7
  const int l = (blockIdx.x & 7) * 64 + (blockIdx.x >> 3);  // bijective XCD remap
  const int bh = l >> 4;             // 0..31 = b*16+h
  const int qt = l & 15;             // 0..15, 128-row q tiles
  const int h = bh & 15;
  const int b = bh >> 4;
  const size_t hoff = (size_t)bh * (SQn * DHn);

  const int c_ = lane & 15, g_ = lane >> 4;
  const int swz = (c_ & 7) << 4;     // P-buffer byte swizzle (bits 4-6)

  const int L = Lb[b];
  const int nt = (L + 63) >> 6;
  const int lastt = nt - 1;

  // Q hoist (B-operand of swapped QK^T): wave's 16 q rows
  bf16x8 qf[2];
  {
    const short* qp = q + hoff + (size_t)(qt * 128 + w * 16 + c_) * DHn + g_ * 8;
    qf[0] = *(const bf16x8*)qp;
    qf[1] = *(const bf16x8*)(qp + 32);
  }

  // staging: 512 chunks per 64x64 tile, 1 per thread for each of K and V
  const int r0 = tid >> 3;
  const int gch = (tid & 7) ^ (r0 & 7);
  const size_t kO = (size_t)r0 * DHn + gch * 8;
  const size_t vO = (size_t)r0 * SKn + gch * 8;
  const int ldsO = tid * 8;

  float mrun = -1e30f;   // running max, common across the 4 lanes of a q-row
  float lrun = 0.f;      // per-lane partial sum
  f32x4 o[4] = {};
  char* PwB = (char*)Ps[w];

#define STAGE(buf, kbase, vbase)            \
  gload16((kbase) + kO, &Ks[buf][ldsO]);    \
  gload16((vbase) + vO, &Vs[buf][ldsO]);

  // ---- prologue: stage tile 0 into buf 0 ----
  const short* kpre = k + hoff;
  const short* vpre = vt + hoff;
  STAGE(0, kpre, vpre);
  kpre += 64 * DHn;
  vpre += 64;
  __syncthreads();

  int cur = 0;
  for (int kt = 0; kt < nt; ++kt) {
    // ---- prefetch tile kt+1 into buf^1 ----
    if (kt + 1 < nt) {
      STAGE(cur ^ 1, kpre, vpre);
      kpre += 64 * DHn;
      vpre += 64;
    }

    const short* Kc = Ks[cur];
    const short* Vc = Vs[cur];

    // ---- S^T = K Q^T : lane holds S[q=c_][key = 16n + 4g_ + i] ----
    f32x4 s[4];
    __builtin_amdgcn_s_setprio(1);
#pragma unroll
    for (int n = 0; n < 4; ++n) {
      f32x4 a = {};
      int key = n * 16 + c_;
#pragma unroll
      for (int kc = 0; kc < 2; ++kc) {
        int slot = (kc * 4 + g_) ^ (key & 7);
        bf16x8 kf = *(const bf16x8*)(Kc + key * 64 + slot * 8);
        a = __builtin_amdgcn_mfma_f32_16x16x32_bf16(kf, qf[kc], a, 0, 0, 0);
      }
      s[n] = a;
    }
    __builtin_amdgcn_s_setprio(0);

    // ---- last-tile index guard (wave-uniform branch) ----
    if (kt == lastt) {
      const int kb = kt * 64 + g_ * 4;
#pragma unroll
      for (int n = 0; n < 4; ++n) {
        const int k0i = kb + n * 16;
        s[n][0] = (k0i + 0 < L) ? s[n][0] : -1e30f;
        s[n][1] = (k0i + 1 < L) ? s[n][1] : -1e30f;
        s[n][2] = (k0i + 2 < L) ? s[n][2] : -1e30f;
        s[n][3] = (k0i + 3 < L) ? s[n][3] : -1e30f;
      }
    }

    // ---- shuffle-free online softmax fast path ----
    float pmax = fmaxf(fmaxf(s[0][0], s[0][1]), fmaxf(s[0][2], s[0][3]));
#pragma unroll
    for (int n = 1; n < 4; ++n)
      pmax = fmaxf(pmax, fmaxf(fmaxf(s[n][0], s[n][1]), fmaxf(s[n][2], s[n][3])));

    if (!__all(pmax - mrun <= 8.f)) {
      float pm = fmaxf(pmax, __shfl_xor(pmax, 16));
      pm = fmaxf(pm, __shfl_xor(pm, 32));      // common per q-row
      float mn = fmaxf(mrun, pm);
      float sc = __builtin_amdgcn_exp2f(mrun - mn);
      mrun = mn;
      lrun *= sc;
      float scB[4];
#pragma unroll
      for (int i = 0; i < 4; ++i) scB[i] = __shfl(sc, g_ * 4 + i);
#pragma unroll
      for (int n = 0; n < 4; ++n)
#pragma unroll
        for (int i = 0; i < 4; ++i) o[n][i] *= scB[i];
    }

    // p = exp2(s - mrun), per-lane partial sum; pack via v_cvt_pk_bf16_f32
    float lsum = 0.f;
#pragma unroll
    for (int n = 0; n < 4; ++n) {
      float p0 = __builtin_amdgcn_exp2f(s[n][0] - mrun);
      float p1 = __builtin_amdgcn_exp2f(s[n][1] - mrun);
      float p2 = __builtin_amdgcn_exp2f(s[n][2] - mrun);
      float p3 = __builtin_amdgcn_exp2f(s[n][3] - mrun);
      lsum += (p0 + p1) + (p2 + p3);
      uint2 pk;
      pk.x = cvt_pk_bf16(p0, p1);
      pk.y = cvt_pk_bf16(p2, p3);
      *(uint2*)(PwB + ((c_ * 128) | ((n * 32 + g_ * 8) ^ swz))) = pk;
    }
    lrun += lsum;

    // ---- O += P V ----
    __builtin_amdgcn_s_setprio(1);
#pragma unroll
    for (int ks = 0; ks < 2; ++ks) {
      bf16x8 pf = *(const bf16x8*)(PwB + ((c_ * 128) | ((ks * 64 + g_ * 16) ^ swz)));
#pragma unroll
      for (int n = 0; n < 4; ++n) {
        int d = n * 16 + c_;
        int slot = (ks * 4 + g_) ^ (d & 7);
        bf16x8 vf = *(const bf16x8*)(Vc + d * 64 + slot * 8);
        o[n] = __builtin_amdgcn_mfma_f32_16x16x32_bf16(pf, vf, o[n], 0, 0, 0);
      }
    }
    __builtin_amdgcn_s_setprio(0);

    __syncthreads();   // drains prefetch vmcnt + P lgkm, flips buffers
    cur ^= 1;
  }

  // ---- epilogue: reduce lrun partials once, then out = o / l ----
  lrun += __shfl_xor(lrun, 16);
  lrun += __shfl_xor(lrun, 32);     // now common per q-row
  float lB[4];
#pragma unroll
  for (int i = 0; i < 4; ++i) lB[i] = __shfl(lrun, g_ * 4 + i);
#pragma unroll
  for (int n = 0; n < 4; ++n) {
#pragma unroll
    for (int i = 0; i < 4; ++i) {
      int srow = qt * 128 + w * 16 + g_ * 4 + i;
      int d = n * 16 + c_;
      out[((size_t)b * SQn + srow) * DMn + h * 64 + d] = f2bf(o[n][i] / lB[i]);
    }
  }
#undef STAGE
}

// ---------------- launch ----------------
extern "C" void kernel_launch(void* const* d_in, const int* in_sizes, int n_in,
                              void* d_out, int out_size, void* d_ws, size_t ws_size,
                              hipStream_t stream) {
  const float* Q  = (const float*)d_in[0];
  const float* K  = (const float*)d_in[1];
  const float* V  = (const float*)d_in[2];
  const int* mask = (const int*)d_in[3];
  const float* Wq = (const float*)d_in[4];
  const float* bq = (const float*)d_in[5];
  const float* Wk = (const float*)d_in[6];
  const float* bk = (const float*)d_in[7];
  const float* Wv = (const float*)d_in[8];
  const float* bv = (const float*)d_in[9];
  const float* Wo = (const float*)d_in[10];
  const float* bo = (const float*)d_in[11];

  char* ws = (char*)d_ws;
  const size_t MB = 1024 * 1024;
  short* Qb  = (short*)(ws + 0 * MB);    // 3 x 8MB contiguous (fused cast out)
  short* Wqt = (short*)(ws + 24 * MB);   // 4 x 2MB contiguous (fused transpose out)
  short* Wkt = (short*)(ws + 26 * MB);
  short* Wvt = (short*)(ws + 28 * MB);
  short* Wot = (short*)(ws + 30 * MB);
  short* qp  = (short*)(ws + 32 * MB);   // [B][H][S][64], pre-scaled
  short* kp  = (short*)(ws + 40 * MB);   // [B][H][S_c][64], key-compacted
  short* vpt = (short*)(ws + 48 * MB);   // [B][H][64][S_c]  (V^T, key-compacted)
  int*   invp = (int*)(ws + 56 * MB);    // [B][2048] inverse partition perm
  int*   Lbp  = (int*)(ws + 56 * MB + 16384);  // [B] valid-key counts
  short* Kb  = Qb + 4 * MB;              // element offsets into fused cast region
  short* Vb  = Qb + 8 * MB;
  short* ao  = Qb;                       // alias: Qb dead after projection GEMM

  // fused preprocessing: QKV casts + 4 weight transposes + mask scan (one launch)
  prep<<<NCASTB + 4096 + 2, 256, 0, stream>>>(Q, K, V, Wq, Wk, Wv, Wo, mask,
                                              Qb, Wqt, invp, Lbp);

  // fused 3-way projection GEMM; 128x256 tiles, gather-compacted, dead blocks exit
  gemm_bt3<<<dim3(32, 4, 3), 512, 0, stream>>>(Qb, Kb, Vb, Wqt, Wkt, Wvt,
                                               bq, bk, bv, qp, kp, vpt,
                                               invp, Lbp);

  attn<<<512, 512, 0, stream>>>(qp, kp, vpt, Lbp, ao);

  // final projection -> f32 output, 128x64 tile = 512 blocks
  gemm_n64<<<dim3(32, 16), 256, 0, stream>>>(ao, Wot, bo, (float*)d_out);
}

// Round 22
// 108.177 us; speedup vs baseline: 1.2653x; 1.2653x over previous
//
#include <hip/hip_runtime.h>
#include <hip/hip_bf16.h>

// Problem constants
#define SQn 2048
#define SKn 2048
#define DMn 1024
#define NHn 16
#define DHn 64

typedef __attribute__((ext_vector_type(8))) short bf16x8;
typedef __attribute__((ext_vector_type(4))) float f32x4;

#define QSCALE 0.1803368801f  /* (1/sqrt(64)) / ln2 : folds softmax scale + exp->exp2 */

#define FBAR()                                     \
  __builtin_amdgcn_sched_barrier(0);               \
  asm volatile("s_barrier" ::: "memory");          \
  __builtin_amdgcn_sched_barrier(0)

__device__ __forceinline__ short f2bf(float f) {
  union { float f; unsigned u; } a; a.f = f;
  return (short)((a.u + 0x7FFFu + ((a.u >> 16) & 1u)) >> 16);  // RNE
}

__device__ __forceinline__ unsigned cvt_pk_bf16(float lo, float hi) {
  unsigned r;
  asm("v_cvt_pk_bf16_f32 %0, %1, %2" : "=v"(r) : "v"(lo), "v"(hi));
  return r;
}

__device__ __forceinline__ void gload16(const void* g, void* l) {
  __builtin_amdgcn_global_load_lds(
      (__attribute__((address_space(1))) void*)g,
      (__attribute__((address_space(3))) void*)l, 16, 0, 0);
}

// ---------------- fused preprocessing: casts + weight transposes + mask scan ----
#define NCASTB 12288
__global__ __launch_bounds__(256) void prep(
    const float* __restrict__ Q, const float* __restrict__ K, const float* __restrict__ V,
    const float* __restrict__ W0, const float* __restrict__ W1,
    const float* __restrict__ W2, const float* __restrict__ W3,
    const int* __restrict__ mask,
    short* __restrict__ qkvOut, short* __restrict__ WtBase,
    int* __restrict__ inv, int* __restrict__ Lb) {
  const int blk = blockIdx.x;
  const int tid = threadIdx.x;
  __shared__ float t[32][33];
  __shared__ int part[256];
  __shared__ int base[256];
  __shared__ int totL;

  if (blk < NCASTB) {
    const int n4each = (2 * 2048 * 1024) / 4;
    int i = blk * 256 + tid;
    const float* src;
    int j = i;
    if (i < n4each) src = Q;
    else if (i < 2 * n4each) { src = K; j = i - n4each; }
    else { src = V; j = i - 2 * n4each; }
    float4 f = ((const float4*)src)[j];
    short4 o;
    o.x = f2bf(f.x); o.y = f2bf(f.y); o.z = f2bf(f.z); o.w = f2bf(f.w);
    ((short4*)qkvOut)[i] = o;
  } else if (blk < NCASTB + 4096) {
    const int tt = blk - NCASTB;
    const int z = tt >> 10;
    const int rem = tt & 1023;
    const float* W = (z == 0) ? W0 : (z == 1) ? W1 : (z == 2) ? W2 : W3;
    short* Wt = WtBase + (size_t)z * DMn * DMn;
    const int bx = (rem & 31) * 32;   // N range
    const int by = (rem >> 5) * 32;   // K range
    const int tx = tid & 31, ty = tid >> 5;  // 32 x 8
#pragma unroll
    for (int j = 0; j < 4; ++j)
      t[ty + j * 8][tx] = W[(size_t)(by + ty + j * 8) * DMn + bx + tx];
    __syncthreads();
#pragma unroll
    for (int j = 0; j < 4; ++j)
      Wt[(size_t)(bx + ty + j * 8) * DMn + by + tx] = f2bf(t[tx][ty + j * 8]);
  } else {
    const int b = blk - NCASTB - 4096;
    const int* m = mask + b * SKn;
    int v[8];
    int s0 = 0;
#pragma unroll
    for (int j = 0; j < 8; ++j) { v[j] = m[tid * 8 + j] ? 1 : 0; s0 += v[j]; }
    part[tid] = s0;
    __syncthreads();
    if (tid == 0) {
      int acc = 0;
      for (int i = 0; i < 256; ++i) { base[i] = acc; acc += part[i]; }
      Lb[b] = acc;
      totL = acc;
    }
    __syncthreads();
    int acc = base[tid];            // # valid keys before this thread's span
    int* ip = inv + b * SKn;
#pragma unroll
    for (int j = 0; j < 8; ++j) {
      int s = tid * 8 + j;
      int c = v[j] ? acc : (totL + s - acc);  // stable partition, bijective
      ip[c] = s;
      acc += v[j];
    }
  }
}

// ---------------- projection GEMM: 128x128, BK=32, 512 thr (r19-verified, 42us) -
// z=0: q (scaled). z=1/2: k / V^T with input-side gather via inv; blocks whose
// compacted rows are all >= L_b exit immediately.
// At its measured delivery ceiling: ~290MB staged at ~6.5TB/s aggregate in the
// 2-blocks/CU overlap regime (r13/r16/r18/r21 all refute structural changes).
__global__ __launch_bounds__(512) void gemm_bt3(
    const short* __restrict__ A0, const short* __restrict__ A1, const short* __restrict__ A2,
    const short* __restrict__ B0, const short* __restrict__ B1, const short* __restrict__ B2,
    const float* __restrict__ c0, const float* __restrict__ c1, const float* __restrict__ c2,
    short* __restrict__ O0, short* __restrict__ O1, short* __restrict__ O2,
    const int* __restrict__ invp, const int* __restrict__ Lp) {
  constexpr int K = 1024;
  const int z = blockIdx.z;
  const int bm = blockIdx.x * 128, bn = blockIdx.y * 128;

  if (z != 0 && (bm & 2047) >= Lp[bm >> 11]) return;

  const short* A  = (z == 0) ? A0 : (z == 1) ? A1 : A2;
  const short* Bt = (z == 0) ? B0 : (z == 1) ? B1 : B2;
  const float* bias = (z == 0) ? c0 : (z == 1) ? c1 : c2;
  short* Cout = (z == 0) ? O0 : (z == 1) ? O1 : O2;

  __shared__ short As[128 * 32];
  __shared__ short Bs[128 * 32];
  const int tid = threadIdx.x;
  const int lane = tid & 63;
  const int wid = tid >> 6;            // 0..7
  const int wr = wid >> 2, wc = wid & 3;   // wave tile 64x32 (2 x 4 waves)

  f32x4 acc[4][2] = {};

  const int srow = tid >> 2;           // 0..127 (compacted row within block)
  const int scol = (tid & 3) * 8;
  int srcRow = bm + srow;
  if (z != 0) srcRow = (srcRow & ~2047) | invp[srcRow];
  const short* Arow = A + (size_t)srcRow * K;
  const short* Brow = Bt + (size_t)(bn + srow) * K;

  for (int k0 = 0; k0 < K; k0 += 32) {
    __syncthreads();
    gload16(Arow + k0 + scol, As + tid * 8);
    gload16(Brow + k0 + scol, Bs + tid * 8);
    __syncthreads();

    bf16x8 a[4], b[2];
    const int rowA = wr * 64 + (lane & 15);
    const int rowB = wc * 32 + (lane & 15);
    const int ko = (lane >> 4) * 8;
#pragma unroll
    for (int m = 0; m < 4; ++m) a[m] = *(const bf16x8*)(As + (rowA + m * 16) * 32 + ko);
#pragma unroll
    for (int n = 0; n < 2; ++n) b[n] = *(const bf16x8*)(Bs + (rowB + n * 16) * 32 + ko);
#pragma unroll
    for (int m = 0; m < 4; ++m)
#pragma unroll
      for (int n = 0; n < 2; ++n)
        acc[m][n] = __builtin_amdgcn_mfma_f32_16x16x32_bf16(a[m], b[n], acc[m][n], 0, 0, 0);
  }

  const int crow0 = bm + wr * 64 + ((lane >> 4) * 4);
  const int ccol0 = bn + wc * 32 + (lane & 15);
  float bv[2];
#pragma unroll
  for (int n = 0; n < 2; ++n) bv[n] = bias[ccol0 + n * 16];
#pragma unroll
  for (int m = 0; m < 4; ++m)
#pragma unroll
    for (int i = 0; i < 4; ++i) {
      int row = crow0 + m * 16 + i;
      int bb = row >> 11, s = row & 2047;   // s = compacted index for z!=0
#pragma unroll
      for (int n = 0; n < 2; ++n) {
        int col = ccol0 + n * 16;
        float val = acc[m][n][i] + bv[n];
        int hh = col >> 6, d = col & 63;    // DH=64
        if (z == 2) {  // V^T: [b][h][d][s_c]
          Cout[((((size_t)bb * NHn + hh) * DHn + d) << 11) + s] = f2bf(val);
        } else {
          if (z == 0) val *= QSCALE;
          Cout[((((size_t)bb * NHn + hh) * SQn + s) << 6) + d] = f2bf(val);
        }
      }
    }
}

// ---------------- final GEMM: 128x64, BK=32, 256 thr, T4 counted-vmcnt ----------
__global__ __launch_bounds__(256) void gemm_n64(const short* __restrict__ A,
                                                const short* __restrict__ Bt,
                                                const float* __restrict__ bias,
                                                float* __restrict__ C) {
  constexpr int K = 1024, N = 1024;
  __shared__ short As[2][128 * 32];
  __shared__ short Bs[2][64 * 32];
  const int tid = threadIdx.x;
  const int lane = tid & 63;
  const int wid = tid >> 6;
  const int wr = wid >> 1, wc = wid & 1;   // waves 2x2, wave tile 64x32
  const int bm = blockIdx.x * 128, bn = blockIdx.y * 64;

  f32x4 acc[4][2] = {};

  const int srow = tid >> 2;               // 0..63
  const int scol = (tid & 3) * 8;
  const short* Ag = A + (size_t)bm * K;
  const short* Bg = Bt + (size_t)bn * K;

#define GSTG(buf, k0)                                                             \
  gload16(Ag + (size_t)srow * K + (k0) + scol,        As[buf] + tid * 8);         \
  gload16(Ag + (size_t)(srow + 64) * K + (k0) + scol, As[buf] + 2048 + tid * 8);  \
  gload16(Bg + (size_t)srow * K + (k0) + scol,        Bs[buf] + tid * 8);

  GSTG(0, 0);
  GSTG(1, 32);

  const int rowA = wr * 64 + (lane & 15);
  const int rowB = wc * 32 + (lane & 15);
  const int ko = (lane >> 4) * 8;

  for (int t = 0; t < 32; ++t) {
    const int cur = t & 1;
    if (t < 31) asm volatile("s_waitcnt vmcnt(3)" ::: "memory");
    else        asm volatile("s_waitcnt vmcnt(0)" ::: "memory");
    FBAR();

    bf16x8 a[4], b[2];
#pragma unroll
    for (int m = 0; m < 4; ++m) a[m] = *(const bf16x8*)(As[cur] + (rowA + m * 16) * 32 + ko);
#pragma unroll
    for (int n = 0; n < 2; ++n) b[n] = *(const bf16x8*)(Bs[cur] + (rowB + n * 16) * 32 + ko);
    __builtin_amdgcn_s_setprio(1);
#pragma unroll
    for (int m = 0; m < 4; ++m)
#pragma unroll
      for (int n = 0; n < 2; ++n)
        acc[m][n] = __builtin_amdgcn_mfma_f32_16x16x32_bf16(a[m], b[n], acc[m][n], 0, 0, 0);
    __builtin_amdgcn_s_setprio(0);

    FBAR();
    if (t < 30) { GSTG(cur, t * 32 + 64); }
  }
#undef GSTG

  const int crow0 = bm + wr * 64 + ((lane >> 4) * 4);
  const int ccol0 = bn + wc * 32 + (lane & 15);
#pragma unroll
  for (int m = 0; m < 4; ++m)
#pragma unroll
    for (int n = 0; n < 2; ++n) {
      int col = ccol0 + n * 16;
      float bv = bias[col];
#pragma unroll
      for (int i = 0; i < 4; ++i) {
        int row = crow0 + m * 16 + i;
        C[(size_t)row * N + col] = acc[m][n][i] + bv;
      }
    }
}

// ---------------- fused flash attention, QBLK=128 (r19-verified config) ---------
// LDS = 2*8K (K) + 2*8K (V) + 16K (P) = 49152; 512 blocks, 2/CU.
__global__ __launch_bounds__(512) void attn(const short* __restrict__ q,
                                            const short* __restrict__ k,
                                            const short* __restrict__ vt,
                                            const int* __restrict__ Lb,
                                            short* __restrict__ out) {
  __shared__ short Ks[2][64 * 64];   // [key][d], chunk-swizzled ^(key&7)
  __shared__ short Vs[2][64 * 64];   // [d][key], chunk-swizzled ^(d&7)
  __shared__ short Ps[8][16 * 64];   // per-wave P, 8B-slot XOR swizzle

  const int tid = threadIdx.x;
  const int lane = tid & 63;
  const int w = tid >> 6;            // 0..7
  const int l = (blockIdx.x & 7) * 64 + (blockIdx.x >> 3);  // bijective XCD remap
  const int bh = l >> 4;             // 0..31 = b*16+h
  const int qt = l & 15;             // 0..15, 128-row q tiles
  const int h = bh & 15;
  const int b = bh >> 4;
  const size_t hoff = (size_t)bh * (SQn * DHn);

  const int c_ = lane & 15, g_ = lane >> 4;
  const int swz = (c_ & 7) << 4;     // P-buffer byte swizzle (bits 4-6)

  const int L = Lb[b];
  const int nt = (L + 63) >> 6;
  const int lastt = nt - 1;

  // Q hoist (B-operand of swapped QK^T): wave's 16 q rows
  bf16x8 qf[2];
  {
    const short* qp = q + hoff + (size_t)(qt * 128 + w * 16 + c_) * DHn + g_ * 8;
    qf[0] = *(const bf16x8*)qp;
    qf[1] = *(const bf16x8*)(qp + 32);
  }

  // staging: 512 chunks per 64x64 tile, 1 per thread for each of K and V
  const int r0 = tid >> 3;
  const int gch = (tid & 7) ^ (r0 & 7);
  const size_t kO = (size_t)r0 * DHn + gch * 8;
  const size_t vO = (size_t)r0 * SKn + gch * 8;
  const int ldsO = tid * 8;

  float mrun = -1e30f;   // running max, common across the 4 lanes of a q-row
  float lrun = 0.f;      // per-lane partial sum
  f32x4 o[4] = {};
  char* PwB = (char*)Ps[w];

#define STAGE(buf, kbase, vbase)            \
  gload16((kbase) + kO, &Ks[buf][ldsO]);    \
  gload16((vbase) + vO, &Vs[buf][ldsO]);

  // ---- prologue: stage tile 0 into buf 0 ----
  const short* kpre = k + hoff;
  const short* vpre = vt + hoff;
  STAGE(0, kpre, vpre);
  kpre += 64 * DHn;
  vpre += 64;
  __syncthreads();

  int cur = 0;
  for (int kt = 0; kt < nt; ++kt) {
    // ---- prefetch tile kt+1 into buf^1 ----
    if (kt + 1 < nt) {
      STAGE(cur ^ 1, kpre, vpre);
      kpre += 64 * DHn;
      vpre += 64;
    }

    const short* Kc = Ks[cur];
    const short* Vc = Vs[cur];

    // ---- S^T = K Q^T : lane holds S[q=c_][key = 16n + 4g_ + i] ----
    f32x4 s[4];
    __builtin_amdgcn_s_setprio(1);
#pragma unroll
    for (int n = 0; n < 4; ++n) {
      f32x4 a = {};
      int key = n * 16 + c_;
#pragma unroll
      for (int kc = 0; kc < 2; ++kc) {
        int slot = (kc * 4 + g_) ^ (key & 7);
        bf16x8 kf = *(const bf16x8*)(Kc + key * 64 + slot * 8);
        a = __builtin_amdgcn_mfma_f32_16x16x32_bf16(kf, qf[kc], a, 0, 0, 0);
      }
      s[n] = a;
    }
    __builtin_amdgcn_s_setprio(0);

    // ---- last-tile index guard (wave-uniform branch) ----
    if (kt == lastt) {
      const int kb = kt * 64 + g_ * 4;
#pragma unroll
      for (int n = 0; n < 4; ++n) {
        const int k0i = kb + n * 16;
        s[n][0] = (k0i + 0 < L) ? s[n][0] : -1e30f;
        s[n][1] = (k0i + 1 < L) ? s[n][1] : -1e30f;
        s[n][2] = (k0i + 2 < L) ? s[n][2] : -1e30f;
        s[n][3] = (k0i + 3 < L) ? s[n][3] : -1e30f;
      }
    }

    // ---- shuffle-free online softmax fast path ----
    float pmax = fmaxf(fmaxf(s[0][0], s[0][1]), fmaxf(s[0][2], s[0][3]));
#pragma unroll
    for (int n = 1; n < 4; ++n)
      pmax = fmaxf(pmax, fmaxf(fmaxf(s[n][0], s[n][1]), fmaxf(s[n][2], s[n][3])));

    if (!__all(pmax - mrun <= 8.f)) {
      float pm = fmaxf(pmax, __shfl_xor(pmax, 16));
      pm = fmaxf(pm, __shfl_xor(pm, 32));      // common per q-row
      float mn = fmaxf(mrun, pm);
      float sc = __builtin_amdgcn_exp2f(mrun - mn);
      mrun = mn;
      lrun *= sc;
      float scB[4];
#pragma unroll
      for (int i = 0; i < 4; ++i) scB[i] = __shfl(sc, g_ * 4 + i);
#pragma unroll
      for (int n = 0; n < 4; ++n)
#pragma unroll
        for (int i = 0; i < 4; ++i) o[n][i] *= scB[i];
    }

    // p = exp2(s - mrun), per-lane partial sum; pack via v_cvt_pk_bf16_f32
    float lsum = 0.f;
#pragma unroll
    for (int n = 0; n < 4; ++n) {
      float p0 = __builtin_amdgcn_exp2f(s[n][0] - mrun);
      float p1 = __builtin_amdgcn_exp2f(s[n][1] - mrun);
      float p2 = __builtin_amdgcn_exp2f(s[n][2] - mrun);
      float p3 = __builtin_amdgcn_exp2f(s[n][3] - mrun);
      lsum += (p0 + p1) + (p2 + p3);
      uint2 pk;
      pk.x = cvt_pk_bf16(p0, p1);
      pk.y = cvt_pk_bf16(p2, p3);
      *(uint2*)(PwB + ((c_ * 128) | ((n * 32 + g_ * 8) ^ swz))) = pk;
    }
    lrun += lsum;

    // ---- O += P V ----
    __builtin_amdgcn_s_setprio(1);
#pragma unroll
    for (int ks = 0; ks < 2; ++ks) {
      bf16x8 pf = *(const bf16x8*)(PwB + ((c_ * 128) | ((ks * 64 + g_ * 16) ^ swz)));
#pragma unroll
      for (int n = 0; n < 4; ++n) {
        int d = n * 16 + c_;
        int slot = (ks * 4 + g_) ^ (d & 7);
        bf16x8 vf = *(const bf16x8*)(Vc + d * 64 + slot * 8);
        o[n] = __builtin_amdgcn_mfma_f32_16x16x32_bf16(pf, vf, o[n], 0, 0, 0);
      }
    }
    __builtin_amdgcn_s_setprio(0);

    __syncthreads();   // drains prefetch vmcnt + P lgkm, flips buffers
    cur ^= 1;
  }

  // ---- epilogue: reduce lrun partials once, then out = o / l ----
  lrun += __shfl_xor(lrun, 16);
  lrun += __shfl_xor(lrun, 32);     // now common per q-row
  float lB[4];
#pragma unroll
  for (int i = 0; i < 4; ++i) lB[i] = __shfl(lrun, g_ * 4 + i);
#pragma unroll
  for (int n = 0; n < 4; ++n) {
#pragma unroll
    for (int i = 0; i < 4; ++i) {
      int srow = qt * 128 + w * 16 + g_ * 4 + i;
      int d = n * 16 + c_;
      out[((size_t)b * SQn + srow) * DMn + h * 64 + d] = f2bf(o[n][i] / lB[i]);
    }
  }
#undef STAGE
}

// ---------------- launch ----------------
extern "C" void kernel_launch(void* const* d_in, const int* in_sizes, int n_in,
                              void* d_out, int out_size, void* d_ws, size_t ws_size,
                              hipStream_t stream) {
  const float* Q  = (const float*)d_in[0];
  const float* K  = (const float*)d_in[1];
  const float* V  = (const float*)d_in[2];
  const int* mask = (const int*)d_in[3];
  const float* Wq = (const float*)d_in[4];
  const float* bq = (const float*)d_in[5];
  const float* Wk = (const float*)d_in[6];
  const float* bk = (const float*)d_in[7];
  const float* Wv = (const float*)d_in[8];
  const float* bv = (const float*)d_in[9];
  const float* Wo = (const float*)d_in[10];
  const float* bo = (const float*)d_in[11];

  char* ws = (char*)d_ws;
  const size_t MB = 1024 * 1024;
  short* Qb  = (short*)(ws + 0 * MB);    // 3 x 8MB contiguous (fused cast out)
  short* Wqt = (short*)(ws + 24 * MB);   // 4 x 2MB contiguous (fused transpose out)
  short* Wkt = (short*)(ws + 26 * MB);
  short* Wvt = (short*)(ws + 28 * MB);
  short* Wot = (short*)(ws + 30 * MB);
  short* qp  = (short*)(ws + 32 * MB);   // [B][H][S][64], pre-scaled
  short* kp  = (short*)(ws + 40 * MB);   // [B][H][S_c][64], key-compacted
  short* vpt = (short*)(ws + 48 * MB);   // [B][H][64][S_c]  (V^T, key-compacted)
  int*   invp = (int*)(ws + 56 * MB);    // [B][2048] inverse partition perm
  int*   Lbp  = (int*)(ws + 56 * MB + 16384);  // [B] valid-key counts
  short* Kb  = Qb + 4 * MB;              // element offsets into fused cast region
  short* Vb  = Qb + 8 * MB;
  short* ao  = Qb;                       // alias: Qb dead after projection GEMM

  // fused preprocessing: QKV casts + 4 weight transposes + mask scan (one launch)
  prep<<<NCASTB + 4096 + 2, 256, 0, stream>>>(Q, K, V, Wq, Wk, Wv, Wo, mask,
                                              Qb, Wqt, invp, Lbp);

  // fused 3-way projection GEMM; k/v input rows gathered via inv, dead blocks exit
  gemm_bt3<<<dim3(32, 8, 3), 512, 0, stream>>>(Qb, Kb, Vb, Wqt, Wkt, Wvt,
                                               bq, bk, bv, qp, kp, vpt,
                                               invp, Lbp);

  attn<<<512, 512, 0, stream>>>(qp, kp, vpt, Lbp, ao);

  // final projection -> f32 output, 128x64 tile = 512 blocks
  gemm_n64<<<dim3(32, 16), 256, 0, stream>>>(ao, Wot, bo, (float*)d_out);
}